// Round 7
// baseline (1424.012 us; speedup 1.0000x reference)
//
#include <hip/hip_runtime.h>
#include <cstddef>
#include <cstdint>

#define NH 9
#define QLD 10  // xu row stride in fp16 (9 + 1 pad -> 20B rows)

typedef _Float16 f16x8 __attribute__((ext_vector_type(8)));
typedef _Float16 f16x2 __attribute__((ext_vector_type(2)));
typedef float f32x4 __attribute__((ext_vector_type(4)));

static const int cN1 = 100000, cN2 = 25000, cN3 = 6250;
static const int cE1 = 1200000, cE2 = 300000, cE3 = 75000;

static inline unsigned ceil_div(size_t a, size_t b) { return (unsigned)((a + b - 1) / b); }

// ---------------- f16 MFMA GEMM: C[M,N] = A[M,K](f32,lda) @ B[K,N](f32,ldb) ----------------
// Optional ridx fuses unpool-gather on A rows. Fragment layout verified (fc_head2, r3-r6).
template <typename CT>
__global__ __launch_bounds__(256) void gemm_mfma(
    const float* __restrict__ A, int lda, const int* __restrict__ ridx,
    const float* __restrict__ B, int ldb,
    CT* __restrict__ C, int ldc, int M, int N, int K)
{
    const int BM = 64, BN = 64, BK = 32, LK = 40;
    __shared__ _Float16 As[BM][LK];
    __shared__ _Float16 Bs[BN][LK];  // transposed: Bs[n][k]
    const int tid = threadIdx.x;
    const int row0 = blockIdx.y * BM, col0 = blockIdx.x * BN;
    const int lane = tid & 63, wv = tid >> 6;
    const int g = lane >> 4, r16 = lane & 15;
    const int wr = wv >> 1, wc = wv & 1;
    f32x4 acc[2][2] = {};
    for (int k0 = 0; k0 < K; k0 += BK) {
        for (int l = tid; l < BM * BK; l += 256) {
            int r = l >> 5, c = l & 31;
            int gr = row0 + r, gk = k0 + c;
            float v = 0.f;
            if (gr < M && gk < K) {
                int ar = ridx ? ridx[gr] : gr;
                v = A[(size_t)ar * lda + gk];
            }
            As[r][c] = (_Float16)v;
        }
        for (int l = tid; l < BK * BN; l += 256) {
            int kk = l >> 6, nn = l & 63;
            int gk = k0 + kk, gn = col0 + nn;
            float v = (gk < K && gn < N) ? B[(size_t)gk * ldb + gn] : 0.f;
            Bs[nn][kk] = (_Float16)v;
        }
        __syncthreads();
        f16x8 af[2], bf[2];
#pragma unroll
        for (int i = 0; i < 2; ++i) af[i] = *(const f16x8*)&As[wr * 32 + i * 16 + r16][g * 8];
#pragma unroll
        for (int j = 0; j < 2; ++j) bf[j] = *(const f16x8*)&Bs[wc * 32 + j * 16 + r16][g * 8];
#pragma unroll
        for (int i = 0; i < 2; ++i)
#pragma unroll
            for (int j = 0; j < 2; ++j)
                acc[i][j] = __builtin_amdgcn_mfma_f32_16x16x32_f16(af[i], bf[j], acc[i][j], 0, 0, 0);
        __syncthreads();
    }
#pragma unroll
    for (int i = 0; i < 2; ++i)
#pragma unroll
        for (int j = 0; j < 2; ++j) {
            int gc = col0 + wc * 32 + j * 16 + r16;
            if (gc >= N) continue;
#pragma unroll
            for (int rr = 0; rr < 4; ++rr) {
                int gr = row0 + wr * 32 + i * 16 + g * 4 + rr;
                if (gr < M) C[(size_t)gr * ldc + gc] = (CT)acc[i][j][rr];
            }
        }
}

// ---------------- counting / hierarchical scan / dual-sort scatter ----------------
__global__ void count_idx(const int* __restrict__ idx, int n, int* __restrict__ cnt)
{
    int i = blockIdx.x * 256 + threadIdx.x;
    if (i < n) atomicAdd(&cnt[idx[i]], 1);
}

__global__ __launch_bounds__(1024) void scan1(const int* __restrict__ in, int* __restrict__ out,
                                              int* __restrict__ part, int n)
{
    __shared__ int wsum[16];
    const int tid = threadIdx.x, lane = tid & 63, wv = tid >> 6;
    int i = blockIdx.x * 1024 + tid;
    int v = (i < n) ? in[i] : 0;
    int acc = v;
#pragma unroll
    for (int off = 1; off < 64; off <<= 1) {
        int t = __shfl_up(acc, off);
        if (lane >= off) acc += t;
    }
    if (lane == 63) wsum[wv] = acc;
    __syncthreads();
    if (wv == 0 && lane < 16) {
        int s = wsum[lane];
        int a2 = s;
#pragma unroll
        for (int off = 1; off < 16; off <<= 1) {
            int t = __shfl_up(a2, off);
            if (lane >= off) a2 += t;
        }
        wsum[lane] = a2 - s;
    }
    __syncthreads();
    int ex = wsum[wv] + acc - v;
    if (i < n) out[i] = ex;
    if (part && tid == 1023) part[blockIdx.x] = ex + v;
}

__global__ void scan_add(int* __restrict__ out, const int* __restrict__ part, int n)
{
    int i = blockIdx.x * 1024 + threadIdx.x;
    if (i < n) out[i] += part[blockIdx.x];
}

// dual scatter: src-sorted edge list (SRCS,DSTS) + dst-CSR -> src-position map (SPOS)
__global__ void scatter_edges2(const int* __restrict__ src, const int* __restrict__ dst, int E,
                               const int* __restrict__ soff, int* __restrict__ curs,
                               const int* __restrict__ doff, int* __restrict__ curd,
                               int* __restrict__ srcs, int* __restrict__ dsts,
                               int* __restrict__ spos)
{
    int e = blockIdx.x * 256 + threadIdx.x;
    if (e >= E) return;
    int s = src[e], d = dst[e];
    int ps = soff[s] + atomicAdd(&curs[s], 1);
    int pd = doff[d] + atomicAdd(&curd[d], 1);
    srcs[ps] = s;
    dsts[ps] = d;
    spos[pd] = ps;
}

// ---------------- Phase 1: per-edge q (inline softmax) + 9-head collapse -> MSG ----------------
// src-sorted order: xw[s]/xu[s] L1-hot across consecutive edges; MSG write coalesced.
template <int OUT>
__global__ __launch_bounds__(256) void feast_msg(
    const int* __restrict__ srcs, const int* __restrict__ dsts, int E,
    const _Float16* __restrict__ xuh, const float* __restrict__ cvec,
    const int* __restrict__ cnt, const _Float16* __restrict__ xw,
    _Float16* __restrict__ msg)
{
    const int T = OUT / 32;  // threads per edge, 32 channels each
    size_t tid = (size_t)blockIdx.x * 256 + threadIdx.x;
    int e = (int)(tid / T);
    int ch = (int)(tid % T);
    if (e >= E) return;
    int s = srcs[e], d = dsts[e];
    const f16x2* us = (const f16x2*)(xuh + (size_t)s * QLD);
    const f16x2* ud = (const f16x2*)(xuh + (size_t)d * QLD);
    float t[NH];
    float m = -1e30f;
#pragma unroll
    for (int i = 0; i < 4; ++i) {
        f16x2 a = us[i], b = ud[i];
        t[2 * i]     = (float)a[0] - (float)b[0] + cvec[2 * i];
        t[2 * i + 1] = (float)a[1] - (float)b[1] + cvec[2 * i + 1];
    }
    t[8] = (float)us[4][0] - (float)ud[4][0] + cvec[8];
#pragma unroll
    for (int h = 0; h < NH; ++h) m = fmaxf(m, t[h]);
    float den = 0.f;
#pragma unroll
    for (int h = 0; h < NH; ++h) { t[h] = __expf(t[h] - m); den += t[h]; }
    float sc = 1.f / (den * (float)(cnt[d] + 1));

    const f16x8* xr = (const f16x8*)(xw + (size_t)s * (NH * OUT) + ch * 32);
    float acc[32] = {};
#pragma unroll
    for (int h = 0; h < NH; ++h) {
        float qh = t[h] * sc;
        const f16x8* xh = xr + h * (OUT / 8);
#pragma unroll
        for (int v = 0; v < 4; ++v) {
            f16x8 x8 = xh[v];
#pragma unroll
            for (int j = 0; j < 8; ++j) acc[v * 8 + j] += qh * (float)x8[j];
        }
    }
    f16x2* mo = (f16x2*)(msg + (size_t)e * OUT + ch * 32);
#pragma unroll
    for (int i = 0; i < 16; ++i) {
        f16x2 r;
        r[0] = (_Float16)acc[2 * i];
        r[1] = (_Float16)acc[2 * i + 1];
        mo[i] = r;
    }
}

// ---------------- Phase 2: CSR permutation-gather reduce + self-loop + bias + act ----------------
// Every MSG row read exactly once (single-touch permutation); xw[d] self-loop rows streamed.
template <int OUT>
__global__ __launch_bounds__(256) void feast_red(
    const int* __restrict__ doff, const int* __restrict__ cnt, const int* __restrict__ spos,
    const _Float16* __restrict__ msg, const _Float16* __restrict__ xw,
    const float* __restrict__ cvec, const float* __restrict__ bias,
    float* __restrict__ outp, int n, int ldo, int col0, int act)
{
    const int L = OUT / 2;
    size_t tid = (size_t)blockIdx.x * 256 + threadIdx.x;
    int d = (int)(tid / L);
    int p = (int)(tid % L);
    if (d >= n) return;
    int beg = doff[d], deg = cnt[d];
    int end = beg + deg;
    float ax = 0.f, ay = 0.f;
    int i = beg;
    for (; i + 2 <= end; i += 2) {
        int p0 = spos[i], p1 = spos[i + 1];
        f16x2 v0 = ((const f16x2*)(msg + (size_t)p0 * OUT))[p];
        f16x2 v1 = ((const f16x2*)(msg + (size_t)p1 * OUT))[p];
        ax += (float)v0[0] + (float)v1[0];
        ay += (float)v0[1] + (float)v1[1];
    }
    if (i < end) {
        int p0 = spos[i];
        f16x2 v0 = ((const f16x2*)(msg + (size_t)p0 * OUT))[p];
        ax += (float)v0[0];
        ay += (float)v0[1];
    }
    // self-loop: softmax(c)/(deg+1) * xw[d]
    float t[NH];
    float m = -1e30f;
#pragma unroll
    for (int h = 0; h < NH; ++h) { t[h] = cvec[h]; m = fmaxf(m, t[h]); }
    float den = 0.f;
#pragma unroll
    for (int h = 0; h < NH; ++h) { t[h] = __expf(t[h] - m); den += t[h]; }
    float sc = 1.f / (den * (float)(deg + 1));
    const f16x2* xd = (const f16x2*)(xw + (size_t)d * (NH * OUT)) + p;
    float mx = 0.f, my = 0.f;
#pragma unroll
    for (int h = 0; h < NH; ++h) {
        f16x2 v = xd[h * (OUT / 2)];
        mx += t[h] * (float)v[0];
        my += t[h] * (float)v[1];
    }
    float vx = ax + mx * sc + bias[2 * p];
    float vy = ay + my * sc + bias[2 * p + 1];
    if (act) {
        vx = vx > 0.f ? vx : 0.1f * vx;
        vy = vy > 0.f ? vy : 0.1f * vy;
    }
    float2* op = (float2*)(outp + (size_t)d * ldo + col0) + p;
    *op = make_float2(vx, vy);
}

// ---------------- pooling ----------------
__global__ void pool_scatter(const float* __restrict__ xin, int ldx, const int* __restrict__ clust,
                             float* __restrict__ pooled, int C, int n)
{
    size_t tid = (size_t)blockIdx.x * 256 + threadIdx.x;
    int i = (int)(tid / C), c = (int)(tid % C);
    if (i >= n) return;
    atomicAdd(&pooled[(size_t)clust[i] * C + c], xin[(size_t)i * ldx + c]);
}

__global__ void pool_div(float* __restrict__ pooled, const int* __restrict__ pcnt, int C, int m)
{
    size_t tid = (size_t)blockIdx.x * 256 + threadIdx.x;
    int j = (int)(tid / C);
    if (j >= m) return;
    pooled[tid] /= fmaxf((float)pcnt[j], 1.f);
}

// ---------------- fc1 weight -> fp16 transposed [1024][32] ----------------
__global__ void w1_to_f16t(const float* __restrict__ w1, _Float16* __restrict__ w1t)
{
    int i = blockIdx.x * 256 + threadIdx.x;
    if (i >= 32 * 1024) return;
    int n = i >> 5, k = i & 31;
    w1t[i] = (_Float16)w1[k * 1024 + n];
}

// ---------------- fused FC head via f16 MFMA: lrelu(y@W1+b1)@W2+b2, row-normalize ----------------
__global__ __launch_bounds__(256) void fc_head2(
    const float* __restrict__ yin, const _Float16* __restrict__ w1t,
    const float* __restrict__ b1, const float* __restrict__ w2,
    const float* __restrict__ b2, float* __restrict__ outp, int n)
{
    const int lane = threadIdx.x & 63, wv = threadIdx.x >> 6;
    const int g = lane >> 4, r16 = lane & 15;
    const int node0 = blockIdx.x * 64 + wv * 16;

    f16x8 afrag;
    int anode = node0 + r16;
    if (anode < n) {
        const float* yr = yin + (size_t)anode * 32 + g * 8;
#pragma unroll
        for (int j = 0; j < 8; ++j) afrag[j] = (_Float16)yr[j];
    } else {
#pragma unroll
        for (int j = 0; j < 8; ++j) afrag[j] = (_Float16)0.f;
    }

    float o0[4] = {0.f, 0.f, 0.f, 0.f};
    float o1[4] = {0.f, 0.f, 0.f, 0.f};
    float o2[4] = {0.f, 0.f, 0.f, 0.f};
    const f32x4 zero4 = {0.f, 0.f, 0.f, 0.f};

#pragma unroll 2
    for (int t = 0; t < 64; ++t) {
        const f16x8 bfrag = *(const f16x8*)(w1t + ((size_t)(t * 16 + r16)) * 32 + g * 8);
        f32x4 d = __builtin_amdgcn_mfma_f32_16x16x32_f16(afrag, bfrag, zero4, 0, 0, 0);
        int kh = t * 16 + r16;
        float b1v = b1[kh];
        float w20 = w2[kh * 3], w21 = w2[kh * 3 + 1], w22 = w2[kh * 3 + 2];
#pragma unroll
        for (int r = 0; r < 4; ++r) {
            float h = d[r] + b1v;
            h = h > 0.f ? h : 0.1f * h;
            o0[r] += h * w20;
            o1[r] += h * w21;
            o2[r] += h * w22;
        }
    }
#pragma unroll
    for (int r = 0; r < 4; ++r) {
#pragma unroll
        for (int off = 1; off < 16; off <<= 1) {
            o0[r] += __shfl_xor(o0[r], off);
            o1[r] += __shfl_xor(o1[r], off);
            o2[r] += __shfl_xor(o2[r], off);
        }
    }
    if (r16 == 0) {
#pragma unroll
        for (int r = 0; r < 4; ++r) {
            int node = node0 + g * 4 + r;
            if (node >= n) continue;
            float v0 = o0[r] + b2[0];
            float v1 = o1[r] + b2[1];
            float v2 = o2[r] + b2[2];
            float nr = fmaxf(sqrtf(v0 * v0 + v1 * v1 + v2 * v2), 1e-12f);
            outp[(size_t)node * 3 + 0] = v0 / nr;
            outp[(size_t)node * 3 + 1] = v1 / nr;
            outp[(size_t)node * 3 + 2] = v2 / nr;
        }
    }
}

// ---------------- dispatch helpers ----------------
static void launch_msg(int outC, const int* srcs, const int* dsts, int E,
                       const _Float16* xuh, const float* cvec, const int* cnt,
                       const _Float16* xw, _Float16* msg, hipStream_t stream)
{
    dim3 g(ceil_div((size_t)E * (outC / 32), 256));
    if (outC == 32)       feast_msg<32><<<g, 256, 0, stream>>>(srcs, dsts, E, xuh, cvec, cnt, xw, msg);
    else if (outC == 64)  feast_msg<64><<<g, 256, 0, stream>>>(srcs, dsts, E, xuh, cvec, cnt, xw, msg);
    else                  feast_msg<128><<<g, 256, 0, stream>>>(srcs, dsts, E, xuh, cvec, cnt, xw, msg);
}

static void launch_red(int outC, const int* doff, const int* cnt, const int* spos,
                       const _Float16* msg, const _Float16* xw, const float* cvec,
                       const float* bias, float* outp, int n, int ldo, int col0,
                       int act, hipStream_t stream)
{
    dim3 g(ceil_div((size_t)n * (outC / 2), 256));
    if (outC == 32)       feast_red<32><<<g, 256, 0, stream>>>(doff, cnt, spos, msg, xw, cvec, bias, outp, n, ldo, col0, act);
    else if (outC == 64)  feast_red<64><<<g, 256, 0, stream>>>(doff, cnt, spos, msg, xw, cvec, bias, outp, n, ldo, col0, act);
    else                  feast_red<128><<<g, 256, 0, stream>>>(doff, cnt, spos, msg, xw, cvec, bias, outp, n, ldo, col0, act);
}

extern "C" void kernel_launch(void* const* d_in, const int* in_sizes, int n_in,
                              void* d_out, int out_size, void* d_ws, size_t ws_size,
                              hipStream_t stream)
{
    const float* x      = (const float*)d_in[0];
    const int*   ei1    = (const int*)d_in[1];
    const int*   ei2    = (const int*)d_in[2];
    const int*   ei3    = (const int*)d_in[3];
    const int*   clust2 = (const int*)d_in[4];
    const int*   clust3 = (const int*)d_in[5];
    const float* lp[8][4];
    for (int i = 0; i < 8; ++i)
        for (int j = 0; j < 4; ++j)
            lp[i][j] = (const float*)d_in[6 + i * 4 + j];  // l1..l4,r1..r4 x {u,c,w,b}
    const float* fc1_w = (const float*)d_in[38];
    const float* fc1_b = (const float*)d_in[39];
    const float* fc2_w = (const float*)d_in[40];
    const float* fc2_b = (const float*)d_in[41];
    float* out = (float*)d_out;

    // ---- workspace layout (~219 MB) ----
    char* ws = (char*)d_ws;
    size_t off = 0;
    auto alloc = [&](size_t b) { size_t p = off; off += (b + 255) & ~(size_t)255; return p; };
    _Float16* XWH = (_Float16*)(ws + alloc((size_t)cN1 * NH * 32 * 2));  // 57.6 MB (max xw, fp16)
    _Float16* MSG = (_Float16*)(ws + alloc((size_t)cE1 * 32 * 2));       // 76.8 MB (max E*OUT fp16)
    _Float16* XUH = (_Float16*)(ws + alloc((size_t)cN1 * QLD * 2));      // 2 MB
    float* GATH  = (float*)(ws + alloc((size_t)cN1 * 32 * 4));           // 12.8 MB (pool scratch; YB alias)
    float* X1CAT = (float*)(ws + alloc((size_t)cN1 * 64 * 4));           // 25.6 MB
    float* X2CAT = (float*)(ws + alloc((size_t)cN2 * 128 * 4));          // 12.8 MB
    float* X2B   = (float*)(ws + alloc((size_t)cN2 * 64 * 4));           // 6.4 MB
    float* X3    = (float*)(ws + alloc((size_t)cN3 * 128 * 4));          // 3.2 MB
    int* SRCS1 = (int*)(ws + alloc((size_t)cE1 * 4));
    int* DSTS1 = (int*)(ws + alloc((size_t)cE1 * 4));
    int* SPOS1 = (int*)(ws + alloc((size_t)cE1 * 4));
    int* SRCS2 = (int*)(ws + alloc((size_t)cE2 * 4));
    int* DSTS2 = (int*)(ws + alloc((size_t)cE2 * 4));
    int* SPOS2 = (int*)(ws + alloc((size_t)cE2 * 4));
    int* SRCS3 = (int*)(ws + alloc((size_t)cE3 * 4));
    int* DSTS3 = (int*)(ws + alloc((size_t)cE3 * 4));
    int* SPOS3 = (int*)(ws + alloc((size_t)cE3 * 4));
    int* DOFF1 = (int*)(ws + alloc((size_t)cN1 * 4));
    int* DOFF2 = (int*)(ws + alloc((size_t)cN2 * 4));
    int* DOFF3 = (int*)(ws + alloc((size_t)cN3 * 4));
    int* SOFF1 = (int*)(ws + alloc((size_t)cN1 * 4));
    int* SOFF2 = (int*)(ws + alloc((size_t)cN2 * 4));
    int* SOFF3 = (int*)(ws + alloc((size_t)cN3 * 4));
    int* CNT1 = (int*)(ws + alloc((size_t)cN1 * 4));
    int* CNT2 = (int*)(ws + alloc((size_t)cN2 * 4));
    int* CNT3 = (int*)(ws + alloc((size_t)cN3 * 4));
    int* SCNT = (int*)(ws + alloc((size_t)cN1 * 4));
    int* CURS = (int*)(ws + alloc((size_t)cN1 * 4));
    int* CURD = (int*)(ws + alloc((size_t)cN1 * 4));
    int* PC2  = (int*)(ws + alloc((size_t)cN2 * 4));
    int* PC3  = (int*)(ws + alloc((size_t)cN3 * 4));
    int* PART = (int*)(ws + alloc(1024 * 4));
    _Float16* W1T = (_Float16*)(ws + alloc((size_t)32 * 1024 * 2));
    float* YB = GATH;  // r4 output aliases pool scratch (free by then)

    auto run_scan = [&](const int* in, int* outp, int n) {
        int nb = (n + 1023) / 1024;
        scan1<<<nb, 1024, 0, stream>>>(in, outp, nb > 1 ? PART : nullptr, n);
        if (nb > 1) {
            scan1<<<1, 1024, 0, stream>>>(PART, PART, nullptr, nb);
            scan_add<<<nb, 1024, 0, stream>>>(outp, PART, n);
        }
    };

    // ---- build per-level: dst counts + dst-CSR offsets, src counts + src offsets, dual scatter ----
    auto build = [&](const int* ei, int E, int n, int* cnt, int* doff, int* soff,
                     int* srcs, int* dsts, int* spos) {
        hipMemsetAsync(cnt, 0, (size_t)n * 4, stream);
        hipMemsetAsync(SCNT, 0, (size_t)n * 4, stream);
        count_idx<<<ceil_div(E, 256), 256, 0, stream>>>(ei + E, E, cnt);   // dst degrees
        count_idx<<<ceil_div(E, 256), 256, 0, stream>>>(ei, E, SCNT);      // src degrees
        run_scan(cnt, doff, n);
        run_scan(SCNT, soff, n);
        hipMemsetAsync(CURS, 0, (size_t)n * 4, stream);
        hipMemsetAsync(CURD, 0, (size_t)n * 4, stream);
        scatter_edges2<<<ceil_div(E, 256), 256, 0, stream>>>(ei, ei + E, E, soff, CURS, doff, CURD, srcs, dsts, spos);
    };
    build(ei1, cE1, cN1, CNT1, DOFF1, SOFF1, SRCS1, DSTS1, SPOS1);
    build(ei2, cE2, cN2, CNT2, DOFF2, SOFF2, SRCS2, DSTS2, SPOS2);
    build(ei3, cE3, cN3, CNT3, DOFF3, SOFF3, SRCS3, DSTS3, SPOS3);

    // fc1 weights -> fp16 transposed
    w1_to_f16t<<<ceil_div(32 * 1024, 256), 256, 0, stream>>>(fc1_w, W1T);

    auto feast = [&](const float* xin, int ldx, const int* ridx, int n, int cin, int outC,
                     const int* srcs, const int* dsts, const int* doff, const int* cnt,
                     const int* spos, int E,
                     const float* const* L, float* dstp, int ldo, int col0, int act) {
        // xu = xin @ u  [n, 9]  (fp16 compact, stride QLD)
        gemm_mfma<_Float16><<<dim3(1, ceil_div(n, 64)), 256, 0, stream>>>(
            xin, ldx, ridx, L[0], NH, XUH, QLD, n, NH, cin);
        // xw = xin @ W  [n, 9*outC]  (fp16)
        int NC = NH * outC;
        gemm_mfma<_Float16><<<dim3(ceil_div(NC, 64), ceil_div(n, 64)), 256, 0, stream>>>(
            xin, ldx, ridx, L[2], NC, XWH, NC, n, NC, cin);
        // phase 1: per-edge q + head-collapse -> MSG (src-sorted, streaming)
        launch_msg(outC, srcs, dsts, E, XUH, L[1], cnt, XWH, MSG, stream);
        // phase 2: CSR permutation-gather reduce + self-loop + bias + act
        launch_red(outC, doff, cnt, spos, MSG, XWH, L[1], L[3], dstp, n, ldo, col0, act, stream);
    };

    // l1: [N1,6] -> [N1,32] into X1CAT[:, 0:32]
    feast(x, 6, nullptr, cN1, 6, 32, SRCS1, DSTS1, DOFF1, CNT1, SPOS1, cE1, lp[0], X1CAT, 64, 0, 1);

    // pool -> [N2,32] in GATH
    hipMemsetAsync(PC2, 0, (size_t)cN2 * 4, stream);
    hipMemsetAsync(GATH, 0, (size_t)cN2 * 32 * 4, stream);
    count_idx<<<ceil_div(cN1, 256), 256, 0, stream>>>(clust2, cN1, PC2);
    pool_scatter<<<ceil_div((size_t)cN1 * 32, 256), 256, 0, stream>>>(X1CAT, 64, clust2, GATH, 32, cN1);
    pool_div<<<ceil_div((size_t)cN2 * 32, 256), 256, 0, stream>>>(GATH, PC2, 32, cN2);

    // l2: [N2,32] -> [N2,64] into X2CAT[:, 0:64]
    feast(GATH, 32, nullptr, cN2, 32, 64, SRCS2, DSTS2, DOFF2, CNT2, SPOS2, cE2, lp[1], X2CAT, 128, 0, 1);

    // pool -> [N3,64] in GATH
    hipMemsetAsync(PC3, 0, (size_t)cN3 * 4, stream);
    hipMemsetAsync(GATH, 0, (size_t)cN3 * 64 * 4, stream);
    count_idx<<<ceil_div(cN2, 256), 256, 0, stream>>>(clust3, cN2, PC3);
    pool_scatter<<<ceil_div((size_t)cN2 * 64, 256), 256, 0, stream>>>(X2CAT, 128, clust3, GATH, 64, cN2);
    pool_div<<<ceil_div((size_t)cN3 * 64, 256), 256, 0, stream>>>(GATH, PC3, 64, cN3);

    // l3: [N3,64] -> [N3,128] into X3
    feast(GATH, 64, nullptr, cN3, 64, 128, SRCS3, DSTS3, DOFF3, CNT3, SPOS3, cE3, lp[2], X3, 128, 0, 1);
    // l4: [N3,128] -> [N3,128] in-place (X3 consumed by gemms before red writes)
    feast(X3, 128, nullptr, cN3, 128, 128, SRCS3, DSTS3, DOFF3, CNT3, SPOS3, cE3, lp[3], X3, 128, 0, 1);

    // r1: feast over unpooled x3 (gather fused via ridx=clust3) -> X2CAT[:, 64:128] (no act)
    feast(X3, 128, clust3, cN2, 128, 64, SRCS2, DSTS2, DOFF2, CNT2, SPOS2, cE2, lp[4], X2CAT, 128, 64, 0);

    // r2: [N2,128] -> [N2,64] into X2B
    feast(X2CAT, 128, nullptr, cN2, 128, 64, SRCS2, DSTS2, DOFF2, CNT2, SPOS2, cE2, lp[5], X2B, 64, 0, 1);

    // r3: feast over unpooled x2 (gather fused via ridx=clust2) -> X1CAT[:, 32:64] (no act)
    feast(X2B, 64, clust2, cN1, 64, 32, SRCS1, DSTS1, DOFF1, CNT1, SPOS1, cE1, lp[6], X1CAT, 64, 32, 0);

    // r4: [N1,64] -> [N1,32] into YB
    feast(X1CAT, 64, nullptr, cN1, 64, 32, SRCS1, DSTS1, DOFF1, CNT1, SPOS1, cE1, lp[7], YB, 32, 0, 1);

    // fused FC head + normalize (f16 MFMA)
    fc_head2<<<ceil_div(cN1, 64), 256, 0, stream>>>(YB, W1T, fc1_b, fc2_w, fc2_b, out, cN1);

    (void)in_sizes; (void)n_in; (void)out_size; (void)ws_size;
}

// Round 8
// 1388.460 us; speedup vs baseline: 1.0256x; 1.0256x over previous
//
#include <hip/hip_runtime.h>
#include <cstddef>
#include <cstdint>

#define NH 9
#define QLD 10  // compact xu row stride in fp16

typedef _Float16 f16x8 __attribute__((ext_vector_type(8)));
typedef _Float16 f16x2 __attribute__((ext_vector_type(2)));
typedef float f32x4 __attribute__((ext_vector_type(4)));

static const int cN1 = 100000, cN2 = 25000, cN3 = 6250;
static const int cE1 = 1200000, cE2 = 300000, cE3 = 75000;

static inline unsigned ceil_div(size_t a, size_t b) { return (unsigned)((a + b - 1) / b); }

// ---------------- Wself[k,o] = sum_h softmax(c)[h] * W[k, h*OUT+o] ----------------
__global__ void make_wself(const float* __restrict__ W, const float* __restrict__ cvec,
                           int K, int OUT, float* __restrict__ ws)
{
    int i = blockIdx.x * 256 + threadIdx.x;
    if (i >= K * OUT) return;
    int k = i / OUT, o = i % OUT;
    float t[NH], m = -1e30f;
#pragma unroll
    for (int h = 0; h < NH; ++h) { t[h] = cvec[h]; m = fmaxf(m, t[h]); }
    float den = 0.f;
#pragma unroll
    for (int h = 0; h < NH; ++h) { t[h] = __expf(t[h] - m); den += t[h]; }
    float acc = 0.f;
#pragma unroll
    for (int h = 0; h < NH; ++h) acc += t[h] * W[(size_t)k * (NH * OUT) + h * OUT + o];
    ws[i] = acc / den;
}

// ---------------- merged f16 MFMA GEMM: C row = [ xW (NC) | x*Wself (OUT) | xu (9) | pad ] ----------------
// B logical [K][NC+OUT+9] assembled from W, WS, U during staging. Optional ridx gathers A rows.
// xu tail is also copied to compact XUH (stride QLD) in the epilogue.
// Fragment layout verified numerically (fc_head2, rounds 3-7).
__global__ __launch_bounds__(256) void gemm_merged(
    const float* __restrict__ A, int lda, const int* __restrict__ ridx,
    const float* __restrict__ W, const float* __restrict__ WS, const float* __restrict__ U,
    _Float16* __restrict__ C, _Float16* __restrict__ xuh,
    int M, int K, int NC, int OUT)
{
    const int N = NC + OUT + NH;
    const int NCO = NC + OUT;
    const int ldc = NCO + 16;
    const int BM = 64, BN = 64, BK = 32, LK = 40;
    __shared__ _Float16 As[BM][LK];
    __shared__ _Float16 Bs[BN][LK];  // transposed: Bs[n][k]
    const int tid = threadIdx.x;
    const int row0 = blockIdx.y * BM, col0 = blockIdx.x * BN;
    const int lane = tid & 63, wv = tid >> 6;
    const int g = lane >> 4, r16 = lane & 15;
    const int wr = wv >> 1, wc = wv & 1;
    f32x4 acc[2][2] = {};
    for (int k0 = 0; k0 < K; k0 += BK) {
        for (int l = tid; l < BM * BK; l += 256) {
            int r = l >> 5, c = l & 31;
            int gr = row0 + r, gk = k0 + c;
            float v = 0.f;
            if (gr < M && gk < K) {
                int ar = ridx ? ridx[gr] : gr;
                v = A[(size_t)ar * lda + gk];
            }
            As[r][c] = (_Float16)v;
        }
        for (int l = tid; l < BK * BN; l += 256) {
            int kk = l >> 6, nn = l & 63;
            int gk = k0 + kk, gn = col0 + nn;
            float v = 0.f;
            if (gk < K && gn < N) {
                if (gn < NC)       v = W[(size_t)gk * NC + gn];
                else if (gn < NCO) v = WS[(size_t)gk * OUT + (gn - NC)];
                else               v = U[(size_t)gk * NH + (gn - NCO)];
            }
            Bs[nn][kk] = (_Float16)v;
        }
        __syncthreads();
        f16x8 af[2], bf[2];
#pragma unroll
        for (int i = 0; i < 2; ++i) af[i] = *(const f16x8*)&As[wr * 32 + i * 16 + r16][g * 8];
#pragma unroll
        for (int j = 0; j < 2; ++j) bf[j] = *(const f16x8*)&Bs[wc * 32 + j * 16 + r16][g * 8];
#pragma unroll
        for (int i = 0; i < 2; ++i)
#pragma unroll
            for (int j = 0; j < 2; ++j)
                acc[i][j] = __builtin_amdgcn_mfma_f32_16x16x32_f16(af[i], bf[j], acc[i][j], 0, 0, 0);
        __syncthreads();
    }
#pragma unroll
    for (int i = 0; i < 2; ++i)
#pragma unroll
        for (int j = 0; j < 2; ++j) {
            int gc = col0 + wc * 32 + j * 16 + r16;
            if (gc >= N) continue;
            int tcol = gc - NCO;
#pragma unroll
            for (int rr = 0; rr < 4; ++rr) {
                int gr = row0 + wr * 32 + i * 16 + g * 4 + rr;
                if (gr >= M) continue;
                _Float16 val = (_Float16)acc[i][j][rr];
                C[(size_t)gr * ldc + gc] = val;
                if (tcol >= 0) xuh[(size_t)gr * QLD + tcol] = val;
            }
        }
}

// ---------------- counting / scan / segment-fill / light scatter ----------------
__global__ void count_idx(const int* __restrict__ idx, int n, int* __restrict__ cnt)
{
    int i = blockIdx.x * 256 + threadIdx.x;
    if (i < n) atomicAdd(&cnt[idx[i]], 1);
}

__global__ void count_both(const int* __restrict__ src, const int* __restrict__ dst, int E,
                           int* __restrict__ scnt, int* __restrict__ dcnt)
{
    int i = blockIdx.x * 256 + threadIdx.x;
    if (i >= E) return;
    atomicAdd(&scnt[src[i]], 1);
    atomicAdd(&dcnt[dst[i]], 1);
}

__global__ __launch_bounds__(1024) void scan1(const int* __restrict__ in, int* __restrict__ out,
                                              int* __restrict__ part, int n)
{
    __shared__ int wsum[16];
    const int tid = threadIdx.x, lane = tid & 63, wv = tid >> 6;
    int i = blockIdx.x * 1024 + tid;
    int v = (i < n) ? in[i] : 0;
    int acc = v;
#pragma unroll
    for (int off = 1; off < 64; off <<= 1) {
        int t = __shfl_up(acc, off);
        if (lane >= off) acc += t;
    }
    if (lane == 63) wsum[wv] = acc;
    __syncthreads();
    if (wv == 0 && lane < 16) {
        int s = wsum[lane];
        int a2 = s;
#pragma unroll
        for (int off = 1; off < 16; off <<= 1) {
            int t = __shfl_up(a2, off);
            if (lane >= off) a2 += t;
        }
        wsum[lane] = a2 - s;
    }
    __syncthreads();
    int ex = wsum[wv] + acc - v;
    if (i < n) out[i] = ex;
    if (part && tid == 1023) part[blockIdx.x] = ex + v;
}

__global__ void scan_add(int* __restrict__ out, const int* __restrict__ part, int n)
{
    int i = blockIdx.x * 1024 + threadIdx.x;
    if (i < n) out[i] += part[blockIdx.x];
}

__global__ void fill_src(const int* __restrict__ soff, const int* __restrict__ scnt,
                         int* __restrict__ srcs, int n)
{
    int i = blockIdx.x * 256 + threadIdx.x;
    if (i >= n) return;
    int b = soff[i], c = scnt[i];
    for (int k = 0; k < c; ++k) srcs[b + k] = i;
}

// 2 random write streams (dsts @ src-pos, spos @ dst-pos); srcs comes from fill_src.
__global__ void scatter_light(const int* __restrict__ src, const int* __restrict__ dst, int E,
                              const int* __restrict__ soff, int* __restrict__ curs,
                              const int* __restrict__ doff, int* __restrict__ curd,
                              int* __restrict__ dsts, int* __restrict__ spos)
{
    int e = blockIdx.x * 256 + threadIdx.x;
    if (e >= E) return;
    int s = src[e], d = dst[e];
    int ps = soff[s] + atomicAdd(&curs[s], 1);
    int pd = doff[d] + atomicAdd(&curd[d], 1);
    dsts[ps] = d;
    spos[pd] = ps;
}

// ---------------- Phase 1: per-edge q (inline softmax) + 9-head collapse -> MSG ----------------
// src-sorted: xwa row s (xw + xu tail) L1-hot across consecutive edges; MSG write coalesced.
template <int OUT>
__global__ __launch_bounds__(256) void feast_msg(
    const int* __restrict__ srcs, const int* __restrict__ dsts, int E,
    const _Float16* __restrict__ xwa, const _Float16* __restrict__ xuh,
    const float* __restrict__ cvec, const int* __restrict__ cnt,
    _Float16* __restrict__ msg)
{
    constexpr int NC = NH * OUT, NCO = NC + OUT, LDR = NCO + 16;
    const int T = OUT / 32;
    size_t tid = (size_t)blockIdx.x * 256 + threadIdx.x;
    int e = (int)(tid / T);
    int ch = (int)(tid % T);
    if (e >= E) return;
    int s = srcs[e], d = dsts[e];
    const f16x2* us = (const f16x2*)(xwa + (size_t)s * LDR + NCO);  // xu[s], same row as xw gather
    const f16x2* ud = (const f16x2*)(xuh + (size_t)d * QLD);        // xu[d], compact L2-resident
    float t[NH];
    float m = -1e30f;
#pragma unroll
    for (int i = 0; i < 4; ++i) {
        f16x2 a = us[i], b = ud[i];
        t[2 * i]     = (float)a[0] - (float)b[0] + cvec[2 * i];
        t[2 * i + 1] = (float)a[1] - (float)b[1] + cvec[2 * i + 1];
    }
    t[8] = (float)us[4][0] - (float)ud[4][0] + cvec[8];
#pragma unroll
    for (int h = 0; h < NH; ++h) m = fmaxf(m, t[h]);
    float den = 0.f;
#pragma unroll
    for (int h = 0; h < NH; ++h) { t[h] = __expf(t[h] - m); den += t[h]; }
    float sc = 1.f / (den * (float)(cnt[d] + 1));

    const f16x8* xrow = (const f16x8*)(xwa + (size_t)s * LDR);
    float acc[32] = {};
#pragma unroll
    for (int h = 0; h < NH; ++h) {
        float qh = t[h] * sc;
        const f16x8* xh = xrow + h * (OUT / 8) + ch * 4;
#pragma unroll
        for (int v = 0; v < 4; ++v) {
            f16x8 x8 = xh[v];
#pragma unroll
            for (int j = 0; j < 8; ++j) acc[v * 8 + j] += qh * (float)x8[j];
        }
    }
    f16x2* mo = (f16x2*)(msg + (size_t)e * OUT + ch * 32);
#pragma unroll
    for (int i = 0; i < 16; ++i) {
        f16x2 r;
        r[0] = (_Float16)acc[2 * i];
        r[1] = (_Float16)acc[2 * i + 1];
        mo[i] = r;
    }
}

// ---------------- Phase 2: CSR permutation-gather reduce + fused self-loop + bias + act ----------------
// Self-loop is one f16x2 load (x*Wself from the GEMM) -- no softmax, no 9-head gather.
template <int OUT>
__global__ __launch_bounds__(256) void feast_red(
    const int* __restrict__ doff, const int* __restrict__ cnt, const int* __restrict__ spos,
    const _Float16* __restrict__ msg, const _Float16* __restrict__ xwa,
    const float* __restrict__ bias, float* __restrict__ outp,
    int n, int ldo, int col0, int act)
{
    constexpr int NC = NH * OUT, NCO = NC + OUT, LDR = NCO + 16;
    const int L = OUT / 2;
    size_t tid = (size_t)blockIdx.x * 256 + threadIdx.x;
    int d = (int)(tid / L);
    int p = (int)(tid % L);
    if (d >= n) return;
    int beg = doff[d], deg = cnt[d];
    int end = beg + deg;
    float ax = 0.f, ay = 0.f;
    int i = beg;
    for (; i + 2 <= end; i += 2) {
        int p0 = spos[i], p1 = spos[i + 1];
        f16x2 v0 = ((const f16x2*)(msg + (size_t)p0 * OUT))[p];
        f16x2 v1 = ((const f16x2*)(msg + (size_t)p1 * OUT))[p];
        ax += (float)v0[0] + (float)v1[0];
        ay += (float)v0[1] + (float)v1[1];
    }
    if (i < end) {
        int p0 = spos[i];
        f16x2 v0 = ((const f16x2*)(msg + (size_t)p0 * OUT))[p];
        ax += (float)v0[0];
        ay += (float)v0[1];
    }
    float sc = 1.f / (float)(deg + 1);
    f16x2 sv = ((const f16x2*)(xwa + (size_t)d * LDR + NC))[p];  // x*Wself
    float vx = ax + (float)sv[0] * sc + bias[2 * p];
    float vy = ay + (float)sv[1] * sc + bias[2 * p + 1];
    if (act) {
        vx = vx > 0.f ? vx : 0.1f * vx;
        vy = vy > 0.f ? vy : 0.1f * vy;
    }
    float2* op = (float2*)(outp + (size_t)d * ldo + col0) + p;
    *op = make_float2(vx, vy);
}

// ---------------- pooling ----------------
__global__ void pool_scatter(const float* __restrict__ xin, int ldx, const int* __restrict__ clust,
                             float* __restrict__ pooled, int C, int n)
{
    size_t tid = (size_t)blockIdx.x * 256 + threadIdx.x;
    int i = (int)(tid / C), c = (int)(tid % C);
    if (i >= n) return;
    atomicAdd(&pooled[(size_t)clust[i] * C + c], xin[(size_t)i * ldx + c]);
}

__global__ void pool_div(float* __restrict__ pooled, const int* __restrict__ pcnt, int C, int m)
{
    size_t tid = (size_t)blockIdx.x * 256 + threadIdx.x;
    int j = (int)(tid / C);
    if (j >= m) return;
    pooled[tid] /= fmaxf((float)pcnt[j], 1.f);
}

// ---------------- fc1 weight -> fp16 transposed [1024][32] ----------------
__global__ void w1_to_f16t(const float* __restrict__ w1, _Float16* __restrict__ w1t)
{
    int i = blockIdx.x * 256 + threadIdx.x;
    if (i >= 32 * 1024) return;
    int n = i >> 5, k = i & 31;
    w1t[i] = (_Float16)w1[k * 1024 + n];
}

// ---------------- fused FC head via f16 MFMA: lrelu(y@W1+b1)@W2+b2, row-normalize ----------------
__global__ __launch_bounds__(256) void fc_head2(
    const float* __restrict__ yin, const _Float16* __restrict__ w1t,
    const float* __restrict__ b1, const float* __restrict__ w2,
    const float* __restrict__ b2, float* __restrict__ outp, int n)
{
    const int lane = threadIdx.x & 63, wv = threadIdx.x >> 6;
    const int g = lane >> 4, r16 = lane & 15;
    const int node0 = blockIdx.x * 64 + wv * 16;

    f16x8 afrag;
    int anode = node0 + r16;
    if (anode < n) {
        const float* yr = yin + (size_t)anode * 32 + g * 8;
#pragma unroll
        for (int j = 0; j < 8; ++j) afrag[j] = (_Float16)yr[j];
    } else {
#pragma unroll
        for (int j = 0; j < 8; ++j) afrag[j] = (_Float16)0.f;
    }

    float o0[4] = {0.f, 0.f, 0.f, 0.f};
    float o1[4] = {0.f, 0.f, 0.f, 0.f};
    float o2[4] = {0.f, 0.f, 0.f, 0.f};
    const f32x4 zero4 = {0.f, 0.f, 0.f, 0.f};

#pragma unroll 2
    for (int t = 0; t < 64; ++t) {
        const f16x8 bfrag = *(const f16x8*)(w1t + ((size_t)(t * 16 + r16)) * 32 + g * 8);
        f32x4 d = __builtin_amdgcn_mfma_f32_16x16x32_f16(afrag, bfrag, zero4, 0, 0, 0);
        int kh = t * 16 + r16;
        float b1v = b1[kh];
        float w20 = w2[kh * 3], w21 = w2[kh * 3 + 1], w22 = w2[kh * 3 + 2];
#pragma unroll
        for (int r = 0; r < 4; ++r) {
            float h = d[r] + b1v;
            h = h > 0.f ? h : 0.1f * h;
            o0[r] += h * w20;
            o1[r] += h * w21;
            o2[r] += h * w22;
        }
    }
#pragma unroll
    for (int r = 0; r < 4; ++r) {
#pragma unroll
        for (int off = 1; off < 16; off <<= 1) {
            o0[r] += __shfl_xor(o0[r], off);
            o1[r] += __shfl_xor(o1[r], off);
            o2[r] += __shfl_xor(o2[r], off);
        }
    }
    if (r16 == 0) {
#pragma unroll
        for (int r = 0; r < 4; ++r) {
            int node = node0 + g * 4 + r;
            if (node >= n) continue;
            float v0 = o0[r] + b2[0];
            float v1 = o1[r] + b2[1];
            float v2 = o2[r] + b2[2];
            float nr = fmaxf(sqrtf(v0 * v0 + v1 * v1 + v2 * v2), 1e-12f);
            outp[(size_t)node * 3 + 0] = v0 / nr;
            outp[(size_t)node * 3 + 1] = v1 / nr;
            outp[(size_t)node * 3 + 2] = v2 / nr;
        }
    }
}

// ---------------- dispatch helpers ----------------
static void launch_msg(int outC, const int* srcs, const int* dsts, int E,
                       const _Float16* xwa, const _Float16* xuh, const float* cvec,
                       const int* cnt, _Float16* msg, hipStream_t stream)
{
    dim3 g(ceil_div((size_t)E * (outC / 32), 256));
    if (outC == 32)       feast_msg<32><<<g, 256, 0, stream>>>(srcs, dsts, E, xwa, xuh, cvec, cnt, msg);
    else if (outC == 64)  feast_msg<64><<<g, 256, 0, stream>>>(srcs, dsts, E, xwa, xuh, cvec, cnt, msg);
    else                  feast_msg<128><<<g, 256, 0, stream>>>(srcs, dsts, E, xwa, xuh, cvec, cnt, msg);
}

static void launch_red(int outC, const int* doff, const int* cnt, const int* spos,
                       const _Float16* msg, const _Float16* xwa, const float* bias,
                       float* outp, int n, int ldo, int col0, int act, hipStream_t stream)
{
    dim3 g(ceil_div((size_t)n * (outC / 2), 256));
    if (outC == 32)       feast_red<32><<<g, 256, 0, stream>>>(doff, cnt, spos, msg, xwa, bias, outp, n, ldo, col0, act);
    else if (outC == 64)  feast_red<64><<<g, 256, 0, stream>>>(doff, cnt, spos, msg, xwa, bias, outp, n, ldo, col0, act);
    else                  feast_red<128><<<g, 256, 0, stream>>>(doff, cnt, spos, msg, xwa, bias, outp, n, ldo, col0, act);
}

extern "C" void kernel_launch(void* const* d_in, const int* in_sizes, int n_in,
                              void* d_out, int out_size, void* d_ws, size_t ws_size,
                              hipStream_t stream)
{
    const float* x      = (const float*)d_in[0];
    const int*   ei1    = (const int*)d_in[1];
    const int*   ei2    = (const int*)d_in[2];
    const int*   ei3    = (const int*)d_in[3];
    const int*   clust2 = (const int*)d_in[4];
    const int*   clust3 = (const int*)d_in[5];
    const float* lp[8][4];
    for (int i = 0; i < 8; ++i)
        for (int j = 0; j < 4; ++j)
            lp[i][j] = (const float*)d_in[6 + i * 4 + j];  // l1..l4,r1..r4 x {u,c,w,b}
    const float* fc1_w = (const float*)d_in[38];
    const float* fc1_b = (const float*)d_in[39];
    const float* fc2_w = (const float*)d_in[40];
    const float* fc2_b = (const float*)d_in[41];
    float* out = (float*)d_out;

    // ---- workspace layout (~229 MB) ----
    char* ws = (char*)d_ws;
    size_t off = 0;
    auto alloc = [&](size_t b) { size_t p = off; off += (b + 255) & ~(size_t)255; return p; };
    _Float16* XWA = (_Float16*)(ws + alloc((size_t)cN1 * 336 * 2));  // 67.2 MB (max rows*ldr: OUT=32 @ N1)
    _Float16* MSG = (_Float16*)(ws + alloc((size_t)cE1 * 32 * 2));   // 76.8 MB
    _Float16* XUH = (_Float16*)(ws + alloc((size_t)cN1 * QLD * 2));  // 2 MB
    float* GATH  = (float*)(ws + alloc((size_t)cN1 * 32 * 4));       // 12.8 MB (pool scratch; YB alias)
    float* X1CAT = (float*)(ws + alloc((size_t)cN1 * 64 * 4));       // 25.6 MB
    float* X2CAT = (float*)(ws + alloc((size_t)cN2 * 128 * 4));      // 12.8 MB
    float* X2B   = (float*)(ws + alloc((size_t)cN2 * 64 * 4));       // 6.4 MB
    float* X3    = (float*)(ws + alloc((size_t)cN3 * 128 * 4));      // 3.2 MB
    int* SRCS1 = (int*)(ws + alloc((size_t)cE1 * 4));
    int* DSTS1 = (int*)(ws + alloc((size_t)cE1 * 4));
    int* SPOS1 = (int*)(ws + alloc((size_t)cE1 * 4));
    int* SRCS2 = (int*)(ws + alloc((size_t)cE2 * 4));
    int* DSTS2 = (int*)(ws + alloc((size_t)cE2 * 4));
    int* SPOS2 = (int*)(ws + alloc((size_t)cE2 * 4));
    int* SRCS3 = (int*)(ws + alloc((size_t)cE3 * 4));
    int* DSTS3 = (int*)(ws + alloc((size_t)cE3 * 4));
    int* SPOS3 = (int*)(ws + alloc((size_t)cE3 * 4));
    int* DOFF1 = (int*)(ws + alloc((size_t)cN1 * 4));
    int* DOFF2 = (int*)(ws + alloc((size_t)cN2 * 4));
    int* DOFF3 = (int*)(ws + alloc((size_t)cN3 * 4));
    int* SOFF1 = (int*)(ws + alloc((size_t)cN1 * 4));
    int* SOFF2 = (int*)(ws + alloc((size_t)cN2 * 4));
    int* SOFF3 = (int*)(ws + alloc((size_t)cN3 * 4));
    // zero-block: CNT1|CNT2|CNT3|PC2|PC3 (one memset)
    int* ZBLK = (int*)(ws + alloc((size_t)(cN1 + cN2 + cN3 + cN2 + cN3) * 4));
    int* CNT1 = ZBLK;
    int* CNT2 = CNT1 + cN1;
    int* CNT3 = CNT2 + cN2;
    int* PC2  = CNT3 + cN3;
    int* PC3  = PC2 + cN2;
    // per-level scratch: SCNT|CURS|CURD (one memset per level)
    int* SCR3 = (int*)(ws + alloc((size_t)cN1 * 3 * 4));
    int* SCNT = SCR3;
    int* CURS = SCR3 + cN1;
    int* CURD = SCR3 + 2 * cN1;
    int* PART = (int*)(ws + alloc(1024 * 4));
    float* WSELF = (float*)(ws + alloc((size_t)47296 * 4));  // 8 layers of K*OUT
    _Float16* W1T = (_Float16*)(ws + alloc((size_t)32 * 1024 * 2));
    float* YB = GATH;  // r4 output aliases pool scratch (free by then)

    auto run_scan = [&](const int* in, int* outp, int n) {
        int nb = (n + 1023) / 1024;
        scan1<<<nb, 1024, 0, stream>>>(in, outp, nb > 1 ? PART : nullptr, n);
        if (nb > 1) {
            scan1<<<1, 1024, 0, stream>>>(PART, PART, nullptr, nb);
            scan_add<<<nb, 1024, 0, stream>>>(outp, PART, n);
        }
    };

    // ---- zero counters (single memsets) ----
    hipMemsetAsync(ZBLK, 0, (size_t)(cN1 + cN2 + cN3 + cN2 + cN3) * 4, stream);

    // ---- per-level build: fused counts, scans, segment-fill srcs, 2-stream scatter ----
    auto build = [&](const int* ei, int E, int n, int* cnt, int* doff, int* soff,
                     int* srcs, int* dsts, int* spos) {
        hipMemsetAsync(SCR3, 0, (size_t)cN1 * 3 * 4, stream);
        count_both<<<ceil_div(E, 256), 256, 0, stream>>>(ei, ei + E, E, SCNT, cnt);
        run_scan(cnt, doff, n);
        run_scan(SCNT, soff, n);
        fill_src<<<ceil_div(n, 256), 256, 0, stream>>>(soff, SCNT, srcs, n);
        scatter_light<<<ceil_div(E, 256), 256, 0, stream>>>(ei, ei + E, E, soff, CURS, doff, CURD, dsts, spos);
    };
    build(ei1, cE1, cN1, CNT1, DOFF1, SOFF1, SRCS1, DSTS1, SPOS1);
    build(ei2, cE2, cN2, CNT2, DOFF2, SOFF2, SRCS2, DSTS2, SPOS2);
    build(ei3, cE3, cN3, CNT3, DOFF3, SOFF3, SRCS3, DSTS3, SPOS3);

    // ---- per-layer Wself precompute (tiny) + fc1 weight transpose ----
    static const int lK[8]   = {6, 32, 64, 128, 128, 128, 64, 64};
    static const int lOUT[8] = {32, 64, 128, 128, 64, 64, 32, 32};
    size_t wsoff[8];
    {
        size_t o = 0;
        for (int i = 0; i < 8; ++i) { wsoff[i] = o; o += (size_t)lK[i] * lOUT[i]; }
    }
    for (int i = 0; i < 8; ++i)
        make_wself<<<ceil_div((size_t)lK[i] * lOUT[i], 256), 256, 0, stream>>>(
            lp[i][2], lp[i][1], lK[i], lOUT[i], WSELF + wsoff[i]);
    w1_to_f16t<<<ceil_div(32 * 1024, 256), 256, 0, stream>>>(fc1_w, W1T);

    auto feast = [&](const float* xin, int ldx, const int* ridx, int n, int cin, int li,
                     const int* srcs, const int* dsts, const int* doff, const int* cnt,
                     const int* spos, int E, float* dstp, int ldo, int col0, int act) {
        int outC = lOUT[li];
        int NC = NH * outC;
        int N = NC + outC + NH;
        gemm_merged<<<dim3(ceil_div(N, 64), ceil_div(n, 64)), 256, 0, stream>>>(
            xin, ldx, ridx, lp[li][2], WSELF + wsoff[li], lp[li][0], XWA, XUH, n, cin, NC, outC);
        launch_msg(outC, srcs, dsts, E, XWA, XUH, lp[li][1], cnt, MSG, stream);
        launch_red(outC, doff, cnt, spos, MSG, XWA, lp[li][3], dstp, n, ldo, col0, act, stream);
    };

    // l1: [N1,6] -> [N1,32] into X1CAT[:, 0:32]
    feast(x, 6, nullptr, cN1, 6, 0, SRCS1, DSTS1, DOFF1, CNT1, SPOS1, cE1, X1CAT, 64, 0, 1);

    // pool -> [N2,32] in GATH
    hipMemsetAsync(GATH, 0, (size_t)cN2 * 32 * 4, stream);
    count_idx<<<ceil_div(cN1, 256), 256, 0, stream>>>(clust2, cN1, PC2);
    pool_scatter<<<ceil_div((size_t)cN1 * 32, 256), 256, 0, stream>>>(X1CAT, 64, clust2, GATH, 32, cN1);
    pool_div<<<ceil_div((size_t)cN2 * 32, 256), 256, 0, stream>>>(GATH, PC2, 32, cN2);

    // l2: [N2,32] -> [N2,64] into X2CAT[:, 0:64]
    feast(GATH, 32, nullptr, cN2, 32, 1, SRCS2, DSTS2, DOFF2, CNT2, SPOS2, cE2, X2CAT, 128, 0, 1);

    // pool -> [N3,64] in GATH
    hipMemsetAsync(GATH, 0, (size_t)cN3 * 64 * 4, stream);
    count_idx<<<ceil_div(cN2, 256), 256, 0, stream>>>(clust3, cN2, PC3);
    pool_scatter<<<ceil_div((size_t)cN2 * 64, 256), 256, 0, stream>>>(X2CAT, 128, clust3, GATH, 64, cN2);
    pool_div<<<ceil_div((size_t)cN3 * 64, 256), 256, 0, stream>>>(GATH, PC3, 64, cN3);

    // l3: [N3,64] -> [N3,128] into X3
    feast(GATH, 64, nullptr, cN3, 64, 2, SRCS3, DSTS3, DOFF3, CNT3, SPOS3, cE3, X3, 128, 0, 1);
    // l4: [N3,128] -> [N3,128] in-place (X3 consumed by gemm before red writes)
    feast(X3, 128, nullptr, cN3, 128, 3, SRCS3, DSTS3, DOFF3, CNT3, SPOS3, cE3, X3, 128, 0, 1);

    // r1: feast over unpooled x3 (gather fused via ridx=clust3) -> X2CAT[:, 64:128] (no act)
    feast(X3, 128, clust3, cN2, 128, 4, SRCS2, DSTS2, DOFF2, CNT2, SPOS2, cE2, X2CAT, 128, 64, 0);

    // r2: [N2,128] -> [N2,64] into X2B
    feast(X2CAT, 128, nullptr, cN2, 128, 5, SRCS2, DSTS2, DOFF2, CNT2, SPOS2, cE2, X2B, 64, 0, 1);

    // r3: feast over unpooled x2 (gather fused via ridx=clust2) -> X1CAT[:, 32:64] (no act)
    feast(X2B, 64, clust2, cN1, 64, 6, SRCS1, DSTS1, DOFF1, CNT1, SPOS1, cE1, X1CAT, 64, 32, 0);

    // r4: [N1,64] -> [N1,32] into YB
    feast(X1CAT, 64, nullptr, cN1, 64, 7, SRCS1, DSTS1, DOFF1, CNT1, SPOS1, cE1, YB, 32, 0, 1);

    // fused FC head + normalize (f16 MFMA)
    fc_head2<<<ceil_div(cN1, 64), 256, 0, stream>>>(YB, W1T, fc1_b, fc2_w, fc2_b, out, cN1);

    (void)in_sizes; (void)n_in; (void)out_size; (void)ws_size;
}

// Round 9
// 1252.697 us; speedup vs baseline: 1.1368x; 1.1084x over previous
//
#include <hip/hip_runtime.h>
#include <cstddef>
#include <cstdint>

#define NH 9
#define QLD 10  // compact xu row stride in fp16

typedef _Float16 f16x8 __attribute__((ext_vector_type(8)));
typedef _Float16 f16x2 __attribute__((ext_vector_type(2)));
typedef float f32x4 __attribute__((ext_vector_type(4)));

static const int cN1 = 100000, cN2 = 25000, cN3 = 6250;
static const int cE1 = 1200000, cE2 = 300000, cE3 = 75000;

static inline unsigned ceil_div(size_t a, size_t b) { return (unsigned)((a + b - 1) / b); }

// ---------------- all-layer Wself[k,o] = sum_h softmax(c)[h] * W[k, h*OUT+o] ----------------
struct WSelfArgs {
    const float* W[8];
    const float* c[8];
    int K[8];
    int OUT[8];
    int base[8];
};

__global__ void make_wself_all(WSelfArgs a, float* __restrict__ ws, int total)
{
    int i = blockIdx.x * 256 + threadIdx.x;
    if (i >= total) return;
    int li = 0;
#pragma unroll
    for (int j = 1; j < 8; ++j) li += (i >= a.base[j]);
    int r = i - a.base[li];
    int OUT = a.OUT[li];
    int k = r / OUT, o = r % OUT;
    const float* cv = a.c[li];
    float t[NH], m = -1e30f;
#pragma unroll
    for (int h = 0; h < NH; ++h) { t[h] = cv[h]; m = fmaxf(m, t[h]); }
    float den = 0.f;
#pragma unroll
    for (int h = 0; h < NH; ++h) { t[h] = __expf(t[h] - m); den += t[h]; }
    const float* W = a.W[li];
    float acc = 0.f;
#pragma unroll
    for (int h = 0; h < NH; ++h) acc += t[h] * W[(size_t)k * (NH * OUT) + h * OUT + o];
    ws[i] = acc / den;
}

// ---------------- merged f16 MFMA GEMM: C row = [ xW (NC) | x*Wself (OUT) | xu (9) | pad ] ----------------
// B logical [K][NC+OUT+9] assembled from W, WS, U during staging. Optional ridx gathers A rows.
// xu tail also copied to compact XUH (stride QLD). Fragment layout verified (fc_head2, r3-r8).
__global__ __launch_bounds__(256) void gemm_merged(
    const float* __restrict__ A, int lda, const int* __restrict__ ridx,
    const float* __restrict__ W, const float* __restrict__ WS, const float* __restrict__ U,
    _Float16* __restrict__ C, _Float16* __restrict__ xuh,
    int M, int K, int NC, int OUT)
{
    const int N = NC + OUT + NH;
    const int NCO = NC + OUT;
    const int ldc = NCO + 16;
    const int BM = 64, BN = 64, BK = 32, LK = 40;
    __shared__ _Float16 As[BM][LK];
    __shared__ _Float16 Bs[BN][LK];  // transposed: Bs[n][k]
    const int tid = threadIdx.x;
    const int row0 = blockIdx.y * BM, col0 = blockIdx.x * BN;
    const int lane = tid & 63, wv = tid >> 6;
    const int g = lane >> 4, r16 = lane & 15;
    const int wr = wv >> 1, wc = wv & 1;
    f32x4 acc[2][2] = {};
    for (int k0 = 0; k0 < K; k0 += BK) {
        for (int l = tid; l < BM * BK; l += 256) {
            int r = l >> 5, c = l & 31;
            int gr = row0 + r, gk = k0 + c;
            float v = 0.f;
            if (gr < M && gk < K) {
                int ar = ridx ? ridx[gr] : gr;
                v = A[(size_t)ar * lda + gk];
            }
            As[r][c] = (_Float16)v;
        }
        for (int l = tid; l < BK * BN; l += 256) {
            int kk = l >> 6, nn = l & 63;
            int gk = k0 + kk, gn = col0 + nn;
            float v = 0.f;
            if (gk < K && gn < N) {
                if (gn < NC)       v = W[(size_t)gk * NC + gn];
                else if (gn < NCO) v = WS[(size_t)gk * OUT + (gn - NC)];
                else               v = U[(size_t)gk * NH + (gn - NCO)];
            }
            Bs[nn][kk] = (_Float16)v;
        }
        __syncthreads();
        f16x8 af[2], bf[2];
#pragma unroll
        for (int i = 0; i < 2; ++i) af[i] = *(const f16x8*)&As[wr * 32 + i * 16 + r16][g * 8];
#pragma unroll
        for (int j = 0; j < 2; ++j) bf[j] = *(const f16x8*)&Bs[wc * 32 + j * 16 + r16][g * 8];
#pragma unroll
        for (int i = 0; i < 2; ++i)
#pragma unroll
            for (int j = 0; j < 2; ++j)
                acc[i][j] = __builtin_amdgcn_mfma_f32_16x16x32_f16(af[i], bf[j], acc[i][j], 0, 0, 0);
        __syncthreads();
    }
#pragma unroll
    for (int i = 0; i < 2; ++i)
#pragma unroll
        for (int j = 0; j < 2; ++j) {
            int gc = col0 + wc * 32 + j * 16 + r16;
            if (gc >= N) continue;
            int tcol = gc - NCO;
#pragma unroll
            for (int rr = 0; rr < 4; ++rr) {
                int gr = row0 + wr * 32 + i * 16 + g * 4 + rr;
                if (gr >= M) continue;
                _Float16 val = (_Float16)acc[i][j][rr];
                C[(size_t)gr * ldc + gc] = val;
                if (tcol >= 0) xuh[(size_t)gr * QLD + tcol] = val;
            }
        }
}

// ---------------- counting / scan / segment-fill / packed scatter ----------------
__global__ void count_idx(const int* __restrict__ idx, int n, int* __restrict__ cnt)
{
    int i = blockIdx.x * 256 + threadIdx.x;
    if (i < n) atomicAdd(&cnt[idx[i]], 1);
}

__global__ void count_both(const int* __restrict__ src, const int* __restrict__ dst, int E,
                           int* __restrict__ scnt, int* __restrict__ dcnt)
{
    int i = blockIdx.x * 256 + threadIdx.x;
    if (i >= E) return;
    atomicAdd(&scnt[src[i]], 1);
    atomicAdd(&dcnt[dst[i]], 1);
}

__global__ __launch_bounds__(1024) void scan1(const int* __restrict__ in, int* __restrict__ out,
                                              int* __restrict__ part, int n)
{
    __shared__ int wsum[16];
    const int tid = threadIdx.x, lane = tid & 63, wv = tid >> 6;
    int i = blockIdx.x * 1024 + tid;
    int v = (i < n) ? in[i] : 0;
    int acc = v;
#pragma unroll
    for (int off = 1; off < 64; off <<= 1) {
        int t = __shfl_up(acc, off);
        if (lane >= off) acc += t;
    }
    if (lane == 63) wsum[wv] = acc;
    __syncthreads();
    if (wv == 0 && lane < 16) {
        int s = wsum[lane];
        int a2 = s;
#pragma unroll
        for (int off = 1; off < 16; off <<= 1) {
            int t = __shfl_up(a2, off);
            if (lane >= off) a2 += t;
        }
        wsum[lane] = a2 - s;
    }
    __syncthreads();
    int ex = wsum[wv] + acc - v;
    if (i < n) out[i] = ex;
    if (part && tid == 1023) part[blockIdx.x] = ex + v;
}

__global__ void scan_add(int* __restrict__ out, const int* __restrict__ part, int n)
{
    int i = blockIdx.x * 1024 + threadIdx.x;
    if (i < n) out[i] += part[blockIdx.x];
}

// srcs[soff[i]-ebias .. ) = i  (soff carries +E bias from the concatenated scan)
__global__ void fill_src(const int* __restrict__ soffB, const int* __restrict__ scnt,
                         int* __restrict__ srcs, int n, int ebias)
{
    int i = blockIdx.x * 256 + threadIdx.x;
    if (i >= n) return;
    int b = soffB[i] - ebias, c = scnt[i];
    for (int k = 0; k < c; ++k) srcs[b + k] = i;
}

// ONE random 8B write per edge: erec[src-pos] = {dst, dst-CSR-pos}.
__global__ void scatter_light(const int* __restrict__ src, const int* __restrict__ dst, int E,
                              const int* __restrict__ soffB, int* __restrict__ curs,
                              const int* __restrict__ doff, int* __restrict__ curd,
                              int2* __restrict__ erec, int ebias)
{
    int e = blockIdx.x * 256 + threadIdx.x;
    if (e >= E) return;
    int s = src[e], d = dst[e];
    int ps = soffB[s] - ebias + atomicAdd(&curs[s], 1);
    int pd = doff[d] + atomicAdd(&curd[d], 1);
    erec[ps] = make_int2(d, pd);
}

// ---------------- Phase 1: per-edge q + 9-head collapse, write MSG at dst-CSR slot ----------------
// src-sorted compute (xwa row L1-hot); write is random but full-line (64-256B rows).
template <int OUT>
__global__ __launch_bounds__(256) void feast_msg(
    const int* __restrict__ srcs, const int2* __restrict__ erec, int E,
    const _Float16* __restrict__ xwa, const _Float16* __restrict__ xuh,
    const float* __restrict__ cvec, const int* __restrict__ cnt,
    _Float16* __restrict__ msg)
{
    constexpr int NC = NH * OUT, NCO = NC + OUT, LDR = NCO + 16;
    const int T = OUT / 32;
    size_t tid = (size_t)blockIdx.x * 256 + threadIdx.x;
    int e = (int)(tid / T);
    int ch = (int)(tid % T);
    if (e >= E) return;
    int s = srcs[e];
    int2 ed = erec[e];
    int d = ed.x, pd = ed.y;
    const f16x2* us = (const f16x2*)(xwa + (size_t)s * LDR + NCO);  // xu[s], same row as xw
    const f16x2* ud = (const f16x2*)(xuh + (size_t)d * QLD);        // xu[d], L2-resident compact
    float t[NH];
    float m = -1e30f;
#pragma unroll
    for (int i = 0; i < 4; ++i) {
        f16x2 a = us[i], b = ud[i];
        t[2 * i]     = (float)a[0] - (float)b[0] + cvec[2 * i];
        t[2 * i + 1] = (float)a[1] - (float)b[1] + cvec[2 * i + 1];
    }
    t[8] = (float)us[4][0] - (float)ud[4][0] + cvec[8];
#pragma unroll
    for (int h = 0; h < NH; ++h) m = fmaxf(m, t[h]);
    float den = 0.f;
#pragma unroll
    for (int h = 0; h < NH; ++h) { t[h] = __expf(t[h] - m); den += t[h]; }
    float sc = 1.f / (den * (float)(cnt[d] + 1));

    const f16x8* xrow = (const f16x8*)(xwa + (size_t)s * LDR);
    float acc[32] = {};
#pragma unroll
    for (int h = 0; h < NH; ++h) {
        float qh = t[h] * sc;
        const f16x8* xh = xrow + h * (OUT / 8) + ch * 4;
#pragma unroll
        for (int v = 0; v < 4; ++v) {
            f16x8 x8 = xh[v];
#pragma unroll
            for (int j = 0; j < 8; ++j) acc[v * 8 + j] += qh * (float)x8[j];
        }
    }
    f16x8* mo = (f16x8*)(msg + (size_t)pd * OUT + ch * 32);
#pragma unroll
    for (int v = 0; v < 4; ++v) {
        f16x8 r;
#pragma unroll
        for (int j = 0; j < 8; ++j) r[j] = (_Float16)acc[v * 8 + j];
        mo[v] = r;
    }
}

// ---------------- Phase 2: fully-contiguous CSR reduce + fused self-loop + bias + act ----------------
template <int OUT>
__global__ __launch_bounds__(256) void feast_red(
    const int* __restrict__ doff, const int* __restrict__ cnt,
    const _Float16* __restrict__ msg, const _Float16* __restrict__ xwa,
    const float* __restrict__ bias, float* __restrict__ outp,
    int n, int ldo, int col0, int act)
{
    constexpr int NC = NH * OUT, LDR = NC + OUT + 16;
    const int L = OUT / 8;
    size_t tid = (size_t)blockIdx.x * 256 + threadIdx.x;
    int d = (int)(tid / L);
    int p = (int)(tid % L);
    if (d >= n) return;
    int beg = doff[d], deg = cnt[d];
    int end = beg + deg;
    float acc[8] = {};
    int i = beg;
    for (; i + 2 <= end; i += 2) {
        f16x8 v0 = *(const f16x8*)(msg + (size_t)i * OUT + p * 8);
        f16x8 v1 = *(const f16x8*)(msg + (size_t)(i + 1) * OUT + p * 8);
#pragma unroll
        for (int j = 0; j < 8; ++j) acc[j] += (float)v0[j] + (float)v1[j];
    }
    if (i < end) {
        f16x8 v0 = *(const f16x8*)(msg + (size_t)i * OUT + p * 8);
#pragma unroll
        for (int j = 0; j < 8; ++j) acc[j] += (float)v0[j];
    }
    float sc = 1.f / (float)(deg + 1);
    f16x8 sv = *(const f16x8*)(xwa + (size_t)d * LDR + NC + p * 8);  // x*Wself
    float o[8];
#pragma unroll
    for (int j = 0; j < 8; ++j) {
        float v = acc[j] + (float)sv[j] * sc + bias[p * 8 + j];
        if (act) v = v > 0.f ? v : 0.1f * v;
        o[j] = v;
    }
    float4* op = (float4*)(outp + (size_t)d * ldo + col0 + p * 8);
    op[0] = make_float4(o[0], o[1], o[2], o[3]);
    op[1] = make_float4(o[4], o[5], o[6], o[7]);
}

// ---------------- pooling ----------------
__global__ void pool_scatter(const float* __restrict__ xin, int ldx, const int* __restrict__ clust,
                             float* __restrict__ pooled, int C, int n)
{
    size_t tid = (size_t)blockIdx.x * 256 + threadIdx.x;
    int i = (int)(tid / C), c = (int)(tid % C);
    if (i >= n) return;
    atomicAdd(&pooled[(size_t)clust[i] * C + c], xin[(size_t)i * ldx + c]);
}

__global__ void pool_div(float* __restrict__ pooled, const int* __restrict__ pcnt, int C, int m)
{
    size_t tid = (size_t)blockIdx.x * 256 + threadIdx.x;
    int j = (int)(tid / C);
    if (j >= m) return;
    pooled[tid] /= fmaxf((float)pcnt[j], 1.f);
}

// ---------------- fc1 weight -> fp16 transposed [1024][32] ----------------
__global__ void w1_to_f16t(const float* __restrict__ w1, _Float16* __restrict__ w1t)
{
    int i = blockIdx.x * 256 + threadIdx.x;
    if (i >= 32 * 1024) return;
    int n = i >> 5, k = i & 31;
    w1t[i] = (_Float16)w1[k * 1024 + n];
}

// ---------------- fused FC head via f16 MFMA: lrelu(y@W1+b1)@W2+b2, row-normalize ----------------
__global__ __launch_bounds__(256) void fc_head2(
    const float* __restrict__ yin, const _Float16* __restrict__ w1t,
    const float* __restrict__ b1, const float* __restrict__ w2,
    const float* __restrict__ b2, float* __restrict__ outp, int n)
{
    const int lane = threadIdx.x & 63, wv = threadIdx.x >> 6;
    const int g = lane >> 4, r16 = lane & 15;
    const int node0 = blockIdx.x * 64 + wv * 16;

    f16x8 afrag;
    int anode = node0 + r16;
    if (anode < n) {
        const float* yr = yin + (size_t)anode * 32 + g * 8;
#pragma unroll
        for (int j = 0; j < 8; ++j) afrag[j] = (_Float16)yr[j];
    } else {
#pragma unroll
        for (int j = 0; j < 8; ++j) afrag[j] = (_Float16)0.f;
    }

    float o0[4] = {0.f, 0.f, 0.f, 0.f};
    float o1[4] = {0.f, 0.f, 0.f, 0.f};
    float o2[4] = {0.f, 0.f, 0.f, 0.f};
    const f32x4 zero4 = {0.f, 0.f, 0.f, 0.f};

#pragma unroll 2
    for (int t = 0; t < 64; ++t) {
        const f16x8 bfrag = *(const f16x8*)(w1t + ((size_t)(t * 16 + r16)) * 32 + g * 8);
        f32x4 d = __builtin_amdgcn_mfma_f32_16x16x32_f16(afrag, bfrag, zero4, 0, 0, 0);
        int kh = t * 16 + r16;
        float b1v = b1[kh];
        float w20 = w2[kh * 3], w21 = w2[kh * 3 + 1], w22 = w2[kh * 3 + 2];
#pragma unroll
        for (int r = 0; r < 4; ++r) {
            float h = d[r] + b1v;
            h = h > 0.f ? h : 0.1f * h;
            o0[r] += h * w20;
            o1[r] += h * w21;
            o2[r] += h * w22;
        }
    }
#pragma unroll
    for (int r = 0; r < 4; ++r) {
#pragma unroll
        for (int off = 1; off < 16; off <<= 1) {
            o0[r] += __shfl_xor(o0[r], off);
            o1[r] += __shfl_xor(o1[r], off);
            o2[r] += __shfl_xor(o2[r], off);
        }
    }
    if (r16 == 0) {
#pragma unroll
        for (int r = 0; r < 4; ++r) {
            int node = node0 + g * 4 + r;
            if (node >= n) continue;
            float v0 = o0[r] + b2[0];
            float v1 = o1[r] + b2[1];
            float v2 = o2[r] + b2[2];
            float nr = fmaxf(sqrtf(v0 * v0 + v1 * v1 + v2 * v2), 1e-12f);
            outp[(size_t)node * 3 + 0] = v0 / nr;
            outp[(size_t)node * 3 + 1] = v1 / nr;
            outp[(size_t)node * 3 + 2] = v2 / nr;
        }
    }
}

// ---------------- dispatch helpers ----------------
static void launch_msg(int outC, const int* srcs, const int2* erec, int E,
                       const _Float16* xwa, const _Float16* xuh, const float* cvec,
                       const int* cnt, _Float16* msg, hipStream_t stream)
{
    dim3 g(ceil_div((size_t)E * (outC / 32), 256));
    if (outC == 32)       feast_msg<32><<<g, 256, 0, stream>>>(srcs, erec, E, xwa, xuh, cvec, cnt, msg);
    else if (outC == 64)  feast_msg<64><<<g, 256, 0, stream>>>(srcs, erec, E, xwa, xuh, cvec, cnt, msg);
    else                  feast_msg<128><<<g, 256, 0, stream>>>(srcs, erec, E, xwa, xuh, cvec, cnt, msg);
}

static void launch_red(int outC, const int* doff, const int* cnt,
                       const _Float16* msg, const _Float16* xwa, const float* bias,
                       float* outp, int n, int ldo, int col0, int act, hipStream_t stream)
{
    dim3 g(ceil_div((size_t)n * (outC / 8), 256));
    if (outC == 32)       feast_red<32><<<g, 256, 0, stream>>>(doff, cnt, msg, xwa, bias, outp, n, ldo, col0, act);
    else if (outC == 64)  feast_red<64><<<g, 256, 0, stream>>>(doff, cnt, msg, xwa, bias, outp, n, ldo, col0, act);
    else                  feast_red<128><<<g, 256, 0, stream>>>(doff, cnt, msg, xwa, bias, outp, n, ldo, col0, act);
}

extern "C" void kernel_launch(void* const* d_in, const int* in_sizes, int n_in,
                              void* d_out, int out_size, void* d_ws, size_t ws_size,
                              hipStream_t stream)
{
    const float* x      = (const float*)d_in[0];
    const int*   ei1    = (const int*)d_in[1];
    const int*   ei2    = (const int*)d_in[2];
    const int*   ei3    = (const int*)d_in[3];
    const int*   clust2 = (const int*)d_in[4];
    const int*   clust3 = (const int*)d_in[5];
    const float* lp[8][4];
    for (int i = 0; i < 8; ++i)
        for (int j = 0; j < 4; ++j)
            lp[i][j] = (const float*)d_in[6 + i * 4 + j];  // l1..l4,r1..r4 x {u,c,w,b}
    const float* fc1_w = (const float*)d_in[38];
    const float* fc1_b = (const float*)d_in[39];
    const float* fc2_w = (const float*)d_in[40];
    const float* fc2_b = (const float*)d_in[41];
    float* out = (float*)d_out;

    // ---- workspace layout (~230 MB) ----
    char* ws = (char*)d_ws;
    size_t off = 0;
    auto alloc = [&](size_t b) { size_t p = off; off += (b + 255) & ~(size_t)255; return p; };
    _Float16* XWA = (_Float16*)(ws + alloc((size_t)cN1 * 336 * 2));  // 67.2 MB (max n*LDR)
    _Float16* MSG = (_Float16*)(ws + alloc((size_t)cE1 * 32 * 2));   // 76.8 MB
    _Float16* XUH = (_Float16*)(ws + alloc((size_t)cN1 * QLD * 2));  // 2 MB
    float* GATH  = (float*)(ws + alloc((size_t)cN1 * 32 * 4));       // 12.8 MB (pool scratch; YB alias)
    float* X1CAT = (float*)(ws + alloc((size_t)cN1 * 64 * 4));       // 25.6 MB
    float* X2CAT = (float*)(ws + alloc((size_t)cN2 * 128 * 4));      // 12.8 MB
    float* X2B   = (float*)(ws + alloc((size_t)cN2 * 64 * 4));       // 6.4 MB
    float* X3    = (float*)(ws + alloc((size_t)cN3 * 128 * 4));      // 3.2 MB
    int* SRCS1 = (int*)(ws + alloc((size_t)cE1 * 4));
    int* SRCS2 = (int*)(ws + alloc((size_t)cE2 * 4));
    int* SRCS3 = (int*)(ws + alloc((size_t)cE3 * 4));
    int2* EREC1 = (int2*)(ws + alloc((size_t)cE1 * 8));
    int2* EREC2 = (int2*)(ws + alloc((size_t)cE2 * 8));
    int2* EREC3 = (int2*)(ws + alloc((size_t)cE3 * 8));
    // combined scan outputs per level: [doff(n) | soff+E(n)]
    int* DS1 = (int*)(ws + alloc((size_t)2 * cN1 * 4));
    int* DS2 = (int*)(ws + alloc((size_t)2 * cN2 * 4));
    int* DS3 = (int*)(ws + alloc((size_t)2 * cN3 * 4));
    // zero-block: [dcnt1|scnt1 | dcnt2|scnt2 | dcnt3|scnt3 | PC2 | PC3] (one memset)
    size_t zn = (size_t)2 * cN1 + 2 * cN2 + 2 * cN3 + cN2 + cN3;
    int* ZBLK = (int*)(ws + alloc(zn * 4));
    int* CB1 = ZBLK;                  // dcnt1 | scnt1
    int* CB2 = CB1 + 2 * cN1;         // dcnt2 | scnt2
    int* CB3 = CB2 + 2 * cN2;         // dcnt3 | scnt3
    int* PC2 = CB3 + 2 * cN3;
    int* PC3 = PC2 + cN2;
    // per-level scratch: CURS|CURD (memset per level)
    int* CUR2 = (int*)(ws + alloc((size_t)2 * cN1 * 4));
    int* PART = (int*)(ws + alloc(1024 * 4));
    float* WSELF = (float*)(ws + alloc((size_t)47296 * 4));
    _Float16* W1T = (_Float16*)(ws + alloc((size_t)32 * 1024 * 2));
    float* YB = GATH;  // r4 output aliases pool scratch (free by then)

    auto run_scan = [&](const int* in, int* outp, int n) {
        int nb = (n + 1023) / 1024;
        scan1<<<nb, 1024, 0, stream>>>(in, outp, nb > 1 ? PART : nullptr, n);
        if (nb > 1) {
            scan1<<<1, 1024, 0, stream>>>(PART, PART, nullptr, nb);
            scan_add<<<nb, 1024, 0, stream>>>(outp, PART, n);
        }
    };

    // ---- zero all counters in ONE memset ----
    hipMemsetAsync(ZBLK, 0, zn * 4, stream);

    // ---- per-level build: fused counts, ONE combined scan, segment-fill, packed scatter ----
    auto build = [&](const int* ei, int E, int n, int* cb, int* ds,
                     int* srcs, int2* erec) {
        hipMemsetAsync(CUR2, 0, (size_t)2 * cN1 * 4, stream);
        count_both<<<ceil_div(E, 256), 256, 0, stream>>>(ei, ei + E, E, cb + n, cb);
        run_scan(cb, ds, 2 * n);  // ds[0:n]=doff ; ds[n:2n]=soff+E
        fill_src<<<ceil_div(n, 256), 256, 0, stream>>>(ds + n, cb + n, srcs, n, E);
        scatter_light<<<ceil_div(E, 256), 256, 0, stream>>>(ei, ei + E, E, ds + n, CUR2, ds, CUR2 + cN1, erec, E);
    };
    build(ei1, cE1, cN1, CB1, DS1, SRCS1, EREC1);
    build(ei2, cE2, cN2, CB2, DS2, SRCS2, EREC2);
    build(ei3, cE3, cN3, CB3, DS3, SRCS3, EREC3);

    // ---- all-layer Wself (one kernel) + fc1 weight transpose ----
    static const int lK[8]   = {6, 32, 64, 128, 128, 128, 64, 64};
    static const int lOUT[8] = {32, 64, 128, 128, 64, 64, 32, 32};
    WSelfArgs wa;
    int wtot = 0;
    for (int i = 0; i < 8; ++i) {
        wa.W[i] = lp[i][2];
        wa.c[i] = lp[i][1];
        wa.K[i] = lK[i];
        wa.OUT[i] = lOUT[i];
        wa.base[i] = wtot;
        wtot += lK[i] * lOUT[i];
    }
    make_wself_all<<<ceil_div(wtot, 256), 256, 0, stream>>>(wa, WSELF, wtot);
    w1_to_f16t<<<ceil_div(32 * 1024, 256), 256, 0, stream>>>(fc1_w, W1T);

    auto feast = [&](const float* xin, int ldx, const int* ridx, int n, int cin, int li,
                     const int* srcs, const int2* erec, const int* ds, const int* cnt, int E,
                     float* dstp, int ldo, int col0, int act) {
        int outC = lOUT[li];
        int NC = NH * outC;
        int N = NC + outC + NH;
        gemm_merged<<<dim3(ceil_div(N, 64), ceil_div(n, 64)), 256, 0, stream>>>(
            xin, ldx, ridx, lp[li][2], WSELF + (size_t)wa.base[li], lp[li][0], XWA, XUH, n, cin, NC, outC);
        launch_msg(outC, srcs, erec, E, XWA, XUH, lp[li][1], cnt, MSG, stream);
        launch_red(outC, ds, cnt, MSG, XWA, lp[li][3], dstp, n, ldo, col0, act, stream);
    };

    // l1: [N1,6] -> [N1,32] into X1CAT[:, 0:32]
    feast(x, 6, nullptr, cN1, 6, 0, SRCS1, EREC1, DS1, CB1, cE1, X1CAT, 64, 0, 1);

    // pool -> [N2,32] in GATH
    hipMemsetAsync(GATH, 0, (size_t)cN2 * 32 * 4, stream);
    count_idx<<<ceil_div(cN1, 256), 256, 0, stream>>>(clust2, cN1, PC2);
    pool_scatter<<<ceil_div((size_t)cN1 * 32, 256), 256, 0, stream>>>(X1CAT, 64, clust2, GATH, 32, cN1);
    pool_div<<<ceil_div((size_t)cN2 * 32, 256), 256, 0, stream>>>(GATH, PC2, 32, cN2);

    // l2: [N2,32] -> [N2,64] into X2CAT[:, 0:64]
    feast(GATH, 32, nullptr, cN2, 32, 1, SRCS2, EREC2, DS2, CB2, cE2, X2CAT, 128, 0, 1);

    // pool -> [N3,64] in GATH
    hipMemsetAsync(GATH, 0, (size_t)cN3 * 64 * 4, stream);
    count_idx<<<ceil_div(cN2, 256), 256, 0, stream>>>(clust3, cN2, PC3);
    pool_scatter<<<ceil_div((size_t)cN2 * 64, 256), 256, 0, stream>>>(X2CAT, 128, clust3, GATH, 64, cN2);
    pool_div<<<ceil_div((size_t)cN3 * 64, 256), 256, 0, stream>>>(GATH, PC3, 64, cN3);

    // l3: [N3,64] -> [N3,128] into X3
    feast(GATH, 64, nullptr, cN3, 64, 2, SRCS3, EREC3, DS3, CB3, cE3, X3, 128, 0, 1);
    // l4: [N3,128] -> [N3,128] in-place (X3 consumed by gemm before red writes)
    feast(X3, 128, nullptr, cN3, 128, 3, SRCS3, EREC3, DS3, CB3, cE3, X3, 128, 0, 1);

    // r1: feast over unpooled x3 (gather fused via ridx=clust3) -> X2CAT[:, 64:128] (no act)
    feast(X3, 128, clust3, cN2, 128, 4, SRCS2, EREC2, DS2, CB2, cE2, X2CAT, 128, 64, 0);

    // r2: [N2,128] -> [N2,64] into X2B
    feast(X2CAT, 128, nullptr, cN2, 128, 5, SRCS2, EREC2, DS2, CB2, cE2, X2B, 64, 0, 1);

    // r3: feast over unpooled x2 (gather fused via ridx=clust2) -> X1CAT[:, 32:64] (no act)
    feast(X2B, 64, clust2, cN1, 64, 6, SRCS1, EREC1, DS1, CB1, cE1, X1CAT, 64, 32, 0);

    // r4: [N1,64] -> [N1,32] into YB
    feast(X1CAT, 64, nullptr, cN1, 64, 7, SRCS1, EREC1, DS1, CB1, cE1, YB, 32, 0, 1);

    // fused FC head + normalize (f16 MFMA)
    fc_head2<<<ceil_div(cN1, 64), 256, 0, stream>>>(YB, W1T, fc1_b, fc2_w, fc2_b, out, cN1);

    (void)in_sizes; (void)n_in; (void)out_size; (void)ws_size;
}